// Round 10
// baseline (317.559 us; speedup 1.0000x reference)
//
#include <hip/hip_runtime.h>
#include <math.h>

#define H 256

__device__ __forceinline__ float sigmoidf_(float x) {
    return 1.0f / (1.0f + __expf(-x));
}

__device__ __forceinline__ float dot4(float4 a, float4 b, float acc) {
    acc = fmaf(a.x, b.x, acc);
    acc = fmaf(a.y, b.y, acc);
    acc = fmaf(a.z, b.z, acc);
    acc = fmaf(a.w, b.w, acc);
    return acc;
}

// Pin a float4 into registers: values become opaque asm outputs, so the
// register allocator CANNOT rematerialize them by re-issuing the load.
#define PIN4(v) asm volatile("" : "+v"((v).x), "+v"((v).y), "+v"((v).z), "+v"((v).w))

// DPP row ops: VALU-pipe cross-lane (NOT the shared DS pipe like __shfl).
// row_shl:n  => dst[i] = src[i+n] within each 16-lane row (data moves toward
// lane 0; bound_ctrl=1 -> out-of-row reads 0). Reduction accumulates at lane 0.
#define ROW_SHL1 0x101
#define ROW_SHL2 0x102
#define ROW_SHL4 0x104
#define ROW_SHL8 0x108

template<int CTRL>
__device__ __forceinline__ float dpp_addf(float v) {
    int s = __builtin_amdgcn_update_dpp(0, __float_as_int(v), CTRL, 0xF, 0xF, true);
    return v + __int_as_float(s);
}
template<int CTRL>
__device__ __forceinline__ float dpp_movf(float v) {
    int s = __builtin_amdgcn_update_dpp(0, __float_as_int(v), CTRL, 0xF, 0xF, true);
    return __int_as_float(s);
}

// ---------------- leaves ----------------
// Wave = 4 j (jl = lane>>4) x 16 k-lanes (ks = lane&15). Block 256 thr = 16 j.
// grid = (16 j-splits, ncoh cohorts). Weights: 48 floats/thread PINNED in VGPRs.
__global__ __launch_bounds__(256, 2) void leaf_kernel(
    const int* __restrict__ word_ids, const float* __restrict__ emb,
    const float* __restrict__ Wi, const float* __restrict__ Wo, const float* __restrict__ Wu,
    const float* __restrict__ bi, const float* __restrict__ bo, const float* __restrict__ bu,
    float* __restrict__ h_buf, int n_leaves, int ncoh)
{
    const int tid  = threadIdx.x;
    const int lane = tid & 63;
    const int wv   = tid >> 6;
    const int ks   = lane & 15;
    const int jl   = lane >> 4;
    const int j    = blockIdx.x * 16 + wv * 4 + jl;
    const int coh  = blockIdx.y;

    float4 wi[4], wo[4], wu[4];
    {
        const float4* pi = (const float4*)(Wi + (size_t)j * H + ks * 16);
        const float4* po = (const float4*)(Wo + (size_t)j * H + ks * 16);
        const float4* pu = (const float4*)(Wu + (size_t)j * H + ks * 16);
#pragma unroll
        for (int c = 0; c < 4; ++c) { wi[c] = pi[c]; wo[c] = po[c]; wu[c] = pu[c]; }
#pragma unroll
        for (int c = 0; c < 4; ++c) { PIN4(wi[c]); PIN4(wo[c]); PIN4(wu[c]); }
    }
    const float bij = bi[j], boj = bo[j], buj = bu[j];

    float4 px[4];
    if (coh < n_leaves) {
        int wid = word_ids[coh];
        const float4* pe = (const float4*)(emb + (size_t)wid * H + ks * 16);
#pragma unroll
        for (int c = 0; c < 4; ++c) px[c] = pe[c];
    }
    for (int l = coh; l < n_leaves; l += ncoh) {
        float ai = 0.f, ao = 0.f, au = 0.f;
#pragma unroll
        for (int c = 0; c < 4; ++c) {
            ai = dot4(px[c], wi[c], ai);
            ao = dot4(px[c], wo[c], ao);
            au = dot4(px[c], wu[c], au);
        }
        int ln = l + ncoh;                // px dead -> refill for next leaf
        if (ln < n_leaves) {
            int wid = word_ids[ln];
            const float4* pe = (const float4*)(emb + (size_t)wid * H + ks * 16);
#pragma unroll
            for (int c = 0; c < 4; ++c) px[c] = pe[c];
        }
        ai = dpp_addf<ROW_SHL8>(ai); ai = dpp_addf<ROW_SHL4>(ai);
        ai = dpp_addf<ROW_SHL2>(ai); ai = dpp_addf<ROW_SHL1>(ai);
        ao = dpp_addf<ROW_SHL8>(ao); ao = dpp_addf<ROW_SHL4>(ao);
        ao = dpp_addf<ROW_SHL2>(ao); ao = dpp_addf<ROW_SHL1>(ao);
        au = dpp_addf<ROW_SHL8>(au); au = dpp_addf<ROW_SHL4>(au);
        au = dpp_addf<ROW_SHL2>(au); au = dpp_addf<ROW_SHL1>(au);
        if (ks == 0) {
            float iv = sigmoidf_(ai + bij);
            float ov = sigmoidf_(ao + boj);
            float uv = fmaxf(au + buj, 0.f);
            float h  = ov * fmaxf(iv * uv, 0.f);
            h_buf[(size_t)l * H + j] = h;
        }
    }
}

// ---------------- one tree level ----------------
// Same shape. Thread weight slice: i,o,u rows (32 k each) + f (Uf1 if ks<8 else Uf2)
// = 128 floats PINNED in registers. x-chunk = cat[ks*32..+31] from h_buf (global).
// Child indices prefetched 2-ahead, x 1-ahead. No LDS, no barriers.
__global__ __launch_bounds__(256, 2) void level_kernel(
    const int* __restrict__ left_idx, const int* __restrict__ right_idx,
    const float* __restrict__ Ui, const float* __restrict__ Uo, const float* __restrict__ Uu,
    const float* __restrict__ Uf1, const float* __restrict__ Uf2,
    const float* __restrict__ bui, const float* __restrict__ buo, const float* __restrict__ buu,
    const float* __restrict__ bf1, const float* __restrict__ bf2,
    float* __restrict__ h_buf, int tbase, int lvl, int n_leaves, int ncoh)
{
    const int tid  = threadIdx.x;
    const int lane = tid & 63;
    const int wv   = tid >> 6;
    const int ks   = lane & 15;
    const int jl   = lane >> 4;
    const int j    = blockIdx.x * 16 + wv * 4 + jl;
    const int coh  = blockIdx.y;

    float4 wi[8], wo[8], wu[8], wf[8];
    {
        const float4* pi = (const float4*)(Ui + (size_t)j * 2 * H + ks * 32);
        const float4* po = (const float4*)(Uo + (size_t)j * 2 * H + ks * 32);
        const float4* pu = (const float4*)(Uu + (size_t)j * 2 * H + ks * 32);
        const float*  fr = (ks < 8) ? (Uf1 + (size_t)j * H + ks * 32)
                                    : (Uf2 + (size_t)j * H + (ks - 8) * 32);
        const float4* pf = (const float4*)fr;
#pragma unroll
        for (int c = 0; c < 8; ++c) { wi[c]=pi[c]; wo[c]=po[c]; wu[c]=pu[c]; wf[c]=pf[c]; }
#pragma unroll
        for (int c = 0; c < 8; ++c) { PIN4(wi[c]); PIN4(wo[c]); PIN4(wu[c]); PIN4(wf[c]); }
    }
    const float b_i = bui[j], b_o = buo[j], b_u = buu[j];
    const float b_1 = bf1[j], b_2 = bf2[j];

    float4 px[8];
    float  plh = 0.f, prh = 0.f;
    int lc2 = 0, rc2 = 0;
    if (coh < lvl) {
        int lc = left_idx[tbase + coh];
        int rc = right_idx[tbase + coh];
        const float4* xb = (const float4*)((ks < 8)
            ? h_buf + (size_t)lc * H + ks * 32
            : h_buf + (size_t)rc * H + (ks - 8) * 32);
#pragma unroll
        for (int c = 0; c < 8; ++c) px[c] = xb[c];
        if (ks == 0) {
            plh = h_buf[(size_t)lc * H + j];
            prh = h_buf[(size_t)rc * H + j];
        }
        int i2 = coh + ncoh;
        if (i2 < lvl) { lc2 = left_idx[tbase + i2]; rc2 = right_idx[tbase + i2]; }
    }

    for (int idx = coh; idx < lvl; idx += ncoh) {
        float lh = plh, rh = prh;
        float ai = 0.f, ao = 0.f, au = 0.f, af = 0.f;
#pragma unroll
        for (int c = 0; c < 8; ++c) {
            ai = dot4(px[c], wi[c], ai);
            ao = dot4(px[c], wo[c], ao);
            au = dot4(px[c], wu[c], au);
            af = dot4(px[c], wf[c], af);
        }
        int idxn = idx + ncoh;            // px dead -> refill for next node
        if (idxn < lvl) {
            const float4* xb = (const float4*)((ks < 8)
                ? h_buf + (size_t)lc2 * H + ks * 32
                : h_buf + (size_t)rc2 * H + (ks - 8) * 32);
#pragma unroll
            for (int c = 0; c < 8; ++c) px[c] = xb[c];
            if (ks == 0) {
                plh = h_buf[(size_t)lc2 * H + j];
                prh = h_buf[(size_t)rc2 * H + j];
            }
            int idx2 = idxn + ncoh;       // indices 2-ahead
            if (idx2 < lvl) { lc2 = left_idx[tbase + idx2]; rc2 = right_idx[tbase + idx2]; }
        }
        // i,o,u: full 16-lane sum -> lane ks==0
        ai = dpp_addf<ROW_SHL8>(ai); ai = dpp_addf<ROW_SHL4>(ai);
        ai = dpp_addf<ROW_SHL2>(ai); ai = dpp_addf<ROW_SHL1>(ai);
        ao = dpp_addf<ROW_SHL8>(ao); ao = dpp_addf<ROW_SHL4>(ao);
        ao = dpp_addf<ROW_SHL2>(ao); ao = dpp_addf<ROW_SHL1>(ao);
        au = dpp_addf<ROW_SHL8>(au); au = dpp_addf<ROW_SHL4>(au);
        au = dpp_addf<ROW_SHL2>(au); au = dpp_addf<ROW_SHL1>(au);
        // f: 8-lane group sums (lane0 = Uf1 part over lanes 0-7,
        // lane8 = Uf2 part over lanes 8-15), then pull f2 to lane 0.
        af = dpp_addf<ROW_SHL4>(af); af = dpp_addf<ROW_SHL2>(af);
        af = dpp_addf<ROW_SHL1>(af);
        float f2s = dpp_movf<ROW_SHL8>(af);   // lane0 <- lane8's sum

        float iv  = sigmoidf_(ai + b_i);
        float ov  = sigmoidf_(ao + b_o);
        float uv  = fmaxf(au + b_u, 0.f);
        float f1v = sigmoidf_(af + b_1);
        float f2v = sigmoidf_(f2s + b_2);
        float cc  = iv * uv + f1v * lh + f2v * rh;
        float h   = ov * fmaxf(cc, 0.f);
        if (ks == 0)
            h_buf[(size_t)(n_leaves + tbase + idx) * H + j] = h;
    }
}

// ---------------- final projection ----------------
__global__ __launch_bounds__(256) void proj_kernel(
    const float* __restrict__ h_buf, const float* __restrict__ Wp,
    const float* __restrict__ bp, float* __restrict__ out, int total)
{
    int t = blockIdx.x * 256 + threadIdx.x;
    if (t >= total) return;
    int node = t / 5;
    int cls  = t - node * 5;
    const float4* hr = (const float4*)(h_buf + (size_t)node * H);
    const float4* wr = (const float4*)(Wp + (size_t)cls * H);
    float acc = 0.f;
#pragma unroll 8
    for (int k = 0; k < H / 4; ++k) {
        float4 a = hr[k], b = wr[k];
        acc += a.x * b.x + a.y * b.y + a.z * b.z + a.w * b.w;
    }
    out[t] = acc + bp[cls];
}

extern "C" void kernel_launch(void* const* d_in, const int* in_sizes, int n_in,
                              void* d_out, int out_size, void* d_ws, size_t ws_size,
                              hipStream_t stream)
{
    const int*   word_ids  = (const int*)  d_in[0];
    const int*   left_idx  = (const int*)  d_in[1];
    const int*   right_idx = (const int*)  d_in[2];
    const float* emb       = (const float*)d_in[3];
    const float* Wi  = (const float*)d_in[4];  const float* bi  = (const float*)d_in[5];
    const float* Wo  = (const float*)d_in[6];  const float* bo  = (const float*)d_in[7];
    const float* Wu  = (const float*)d_in[8];  const float* bu  = (const float*)d_in[9];
    const float* Ui  = (const float*)d_in[10]; const float* bui = (const float*)d_in[11];
    const float* Uo  = (const float*)d_in[12]; const float* buo = (const float*)d_in[13];
    const float* Uu  = (const float*)d_in[14]; const float* buu = (const float*)d_in[15];
    const float* Uf1 = (const float*)d_in[16]; const float* bf1 = (const float*)d_in[17];
    const float* Uf2 = (const float*)d_in[18]; const float* bf2 = (const float*)d_in[19];
    const float* Wp  = (const float*)d_in[20]; const float* bp  = (const float*)d_in[21];

    const int n_leaves   = in_sizes[0];
    const int n_internal = in_sizes[1];
    const int n_nodes    = n_leaves + n_internal;
    (void)n_in; (void)out_size; (void)ws_size;

    float* h_buf = (float*)d_ws;   // [n_nodes][H]

    // 1) leaves
    int ncohL = n_leaves < 64 ? n_leaves : 64;
    leaf_kernel<<<dim3(16, ncohL), 256, 0, stream>>>(
        word_ids, emb, Wi, Wo, Wu, bi, bo, bu, h_buf, n_leaves, ncohL);

    // 2) internal levels (stream order = level dependency)
    int frontier = n_leaves;
    int tbase = 0;
    while (frontier > 1) {
        int lvl  = frontier >> 1;
        int ncoh = lvl < 64 ? lvl : 64;
        level_kernel<<<dim3(16, ncoh), 256, 0, stream>>>(
            left_idx, right_idx, Ui, Uo, Uu, Uf1, Uf2,
            bui, buo, buu, bf1, bf2, h_buf, tbase, lvl, n_leaves, ncoh);
        tbase += lvl;
        frontier = lvl + (frontier & 1);
    }

    // 3) projection
    int total = n_nodes * 5;
    proj_kernel<<<(total + 255) / 256, 256, 0, stream>>>(h_buf, Wp, bp, (float*)d_out, total);
}